// Round 1
// baseline (1696.146 us; speedup 1.0000x reference)
//
#include <hip/hip_runtime.h>
#include <math.h>

// Problem constants
#define NT   8192          // N*T rows
#define UV   4096          // U*B cells
#define SDIM 128
#define LOG1EM6 -13.815510557964274f

// d_out layout (float offsets): delta[8192][256], sig[8192][128], conf[8192],
// weights[8192][4096], topw[8192]
#define O_DELTA 0
#define O_SIG   2097152
#define O_CONF  3145728
#define O_W     3153920
#define O_TOPW  36708352

// d_ws layout (float offsets)
#define W_SPNT  0              // normalized signature proto, transposed [128][4096]
#define W_QST   524288         // normalized q_sigma, transposed [128][8192]
#define W_BIAS  1572864        // 0.5*usage_n + 0.5*conf_n  [4096]
#define W_CONFN 1576960        // conf_n [4096]
#define W_VALID 1581056        // validity (write_mass>0) [4096]
#define W_PSUM  1585152        // per-half row partial sums [2][8192]
#define W_PMAX  1601536        // per-half row partial max logit [2][8192]
#define W_PSIG  1617920        // sig at partial argmax [2][8192]
#define W_PUV   1634304        // uv index (as float) at partial argmax [2][8192]

// ---------------------------------------------------------------------------
// K1: global maxes over write_mass/ema_conf -> bias/conf/valid tables.
// ---------------------------------------------------------------------------
__global__ void k1_tables(const float* __restrict__ wm,
                          const float* __restrict__ ec,
                          float* __restrict__ ws)
{
    __shared__ float red1[256];
    __shared__ float red2[256];
    const int tid = threadIdx.x;
    float m1 = 0.0f, m2 = 0.0f;      // log1p(wm) >= 0, ema_conf >= 0
    for (int i = tid; i < UV; i += 256) {
        m1 = fmaxf(m1, log1pf(wm[i]));
        m2 = fmaxf(m2, ec[i]);
    }
    red1[tid] = m1; red2[tid] = m2;
    __syncthreads();
    for (int s = 128; s > 0; s >>= 1) {
        if (tid < s) {
            red1[tid] = fmaxf(red1[tid], red1[tid + s]);
            red2[tid] = fmaxf(red2[tid], red2[tid + s]);
        }
        __syncthreads();
    }
    const float inv1 = 1.0f / fmaxf(red1[0], 1.0f);
    const float inv2 = 1.0f / fmaxf(red2[0], 1e-6f);
    for (int i = tid; i < UV; i += 256) {
        float w  = wm[i];
        float un = log1pf(w) * inv1;
        float cn = ec[i] * inv2;
        ws[W_BIAS  + i] = 0.5f * un + 0.5f * cn;
        ws[W_CONFN + i] = cn;
        ws[W_VALID + i] = (w > 0.0f) ? 1.0f : 0.0f;
    }
}

// ---------------------------------------------------------------------------
// K2: l2-normalize signature_proto(+1e-6) and q_sigma rows; write TRANSPOSED
// ([s][uv] / [s][row]) for coalesced GEMM1 staging. One 64-lane wave per row.
// ---------------------------------------------------------------------------
__global__ void k2_norm(const float* __restrict__ spr,
                        const float* __restrict__ qsig,
                        float* __restrict__ ws)
{
    const int wid  = blockIdx.x * 4 + (threadIdx.x >> 6);   // 0..12287
    const int lane = threadIdx.x & 63;
    if (wid < UV) {
        const float* src = spr + (size_t)wid * SDIM;
        float a = src[lane] + 1e-6f;
        float b = src[lane + 64] + 1e-6f;
        float ss = a * a + b * b;
        for (int m = 32; m > 0; m >>= 1) ss += __shfl_xor(ss, m);
        float inv = 1.0f / fmaxf(sqrtf(ss), 1e-12f);
        ws[W_SPNT + lane * UV + wid]        = a * inv;
        ws[W_SPNT + (lane + 64) * UV + wid] = b * inv;
    } else {
        const int row = wid - UV;
        const float* src = qsig + (size_t)row * SDIM;
        float a = src[lane];
        float b = src[lane + 64];
        float ss = a * a + b * b;
        for (int m = 32; m > 0; m >>= 1) ss += __shfl_xor(ss, m);
        float inv = 1.0f / fmaxf(sqrtf(ss), 1e-12f);
        ws[W_QST + lane * NT + row]        = a * inv;
        ws[W_QST + (lane + 64) * NT + row] = b * inv;
    }
}

// ---------------------------------------------------------------------------
// K3: GEMM1 (qs . spn^T) fused with logits + fixed-shift exp. Tile: 32 rows x
// 2048 uv per block (grid 256x2 halves -> 512 blocks, 2/CU). 128 threads,
// micro-tile 4x4 (FMA:LDS-instr = 16:2, LDS reads broadcast-heavy).
// Writes unnormalized e to weights region + per-half row stats to ws.
// ---------------------------------------------------------------------------
__global__ __launch_bounds__(128)
void k3_main(const float* __restrict__ qu, const float* __restrict__ qb,
             float* __restrict__ ws, float* __restrict__ dout)
{
    extern __shared__ float smem[];
    float* lA = smem;          // qsT chunk [128 s][32 r]      (16 KB)
    float* lB = smem + 4096;   // spnT chunk [128 s][64 j]     (32 KB)

    const int tid  = threadIdx.x;
    const int row0 = blockIdx.x * 32;
    const int h    = blockIdx.y;             // uv half: chunks [h*32, h*32+32)
    const float* qsT   = ws + W_QST;
    const float* spnT  = ws + W_SPNT;
    const float* bias  = ws + W_BIAS;
    const float* validf= ws + W_VALID;
    float* wout = dout + O_W;

    // Stage A (full K=128 for our 32 rows)
    for (int idx = tid; idx < 128 * 32; idx += 128) {
        int s = idx >> 5, r = idx & 31;
        lA[idx] = qsT[s * NT + row0 + r];
    }

    const int trr = tid >> 4;   // 0..7  -> rows trr*4 + i
    const int tcc = tid & 15;   // 0..15 -> cols tcc*4 + j
    float psum[4] = {0, 0, 0, 0};
    float pmax[4] = {-1e30f, -1e30f, -1e30f, -1e30f};
    float psig[4] = {0, 0, 0, 0};
    unsigned puv[4] = {0, 0, 0, 0};

    for (int c = h * 32; c < h * 32 + 32; ++c) {
        __syncthreads();
        for (int idx = tid; idx < 128 * 64; idx += 128) {
            int s = idx >> 6, j = idx & 63;
            lB[idx] = spnT[s * UV + c * 64 + j];
        }
        __syncthreads();

        float acc[4][4] = {{0,0,0,0},{0,0,0,0},{0,0,0,0},{0,0,0,0}};
        #pragma unroll 8
        for (int s = 0; s < 128; ++s) {
            const float4 a = *(const float4*)&lA[s * 32 + trr * 4];
            const float4 b = *(const float4*)&lB[s * 64 + tcc * 4];
            acc[0][0] = fmaf(a.x, b.x, acc[0][0]);
            acc[0][1] = fmaf(a.x, b.y, acc[0][1]);
            acc[0][2] = fmaf(a.x, b.z, acc[0][2]);
            acc[0][3] = fmaf(a.x, b.w, acc[0][3]);
            acc[1][0] = fmaf(a.y, b.x, acc[1][0]);
            acc[1][1] = fmaf(a.y, b.y, acc[1][1]);
            acc[1][2] = fmaf(a.y, b.z, acc[1][2]);
            acc[1][3] = fmaf(a.y, b.w, acc[1][3]);
            acc[2][0] = fmaf(a.z, b.x, acc[2][0]);
            acc[2][1] = fmaf(a.z, b.y, acc[2][1]);
            acc[2][2] = fmaf(a.z, b.z, acc[2][2]);
            acc[2][3] = fmaf(a.z, b.w, acc[2][3]);
            acc[3][0] = fmaf(a.w, b.x, acc[3][0]);
            acc[3][1] = fmaf(a.w, b.y, acc[3][1]);
            acc[3][2] = fmaf(a.w, b.z, acc[3][2]);
            acc[3][3] = fmaf(a.w, b.w, acc[3][3]);
        }

        // Epilogue: chunk c covers uv in [c*64, c*64+64) -> u = c, v = col.
        const int u = c;
        const float4 b4 = *(const float4*)&bias[c * 64 + tcc * 4];
        const float4 v4 = *(const float4*)&validf[c * 64 + tcc * 4];
        const float bl[4] = {b4.x, b4.y, b4.z, b4.w};
        const float vl[4] = {v4.x, v4.y, v4.z, v4.w};
        #pragma unroll
        for (int i = 0; i < 4; ++i) {
            const int row = row0 + trr * 4 + i;
            const float lqu = __logf(qu[(size_t)row * 64 + u]);
            const float4 qb4 = *(const float4*)&qb[(size_t)row * 64 + tcc * 4];
            const float qbl[4] = {qb4.x, qb4.y, qb4.z, qb4.w};
            float e4[4];
            #pragma unroll
            for (int j = 0; j < 4; ++j) {
                float jl  = fmaxf(lqu + __logf(qbl[j]), LOG1EM6);
                float sig = fmaf(0.5f, acc[i][j], 0.5f);
                float lg  = jl + bl[j] + sig;
                bool  vd  = vl[j] > 0.0f;
                float e   = vd ? __expf(lg - 2.0f) : 0.0f;   // logit <= 2 always
                e4[j] = e;
                psum[i] += e;
                if (vd && lg > pmax[i]) {
                    pmax[i] = lg;
                    puv[i]  = (unsigned)(c * 64 + tcc * 4 + j);
                    psig[i] = sig;
                }
            }
            *(float4*)&wout[(size_t)row * UV + c * 64 + tcc * 4] =
                make_float4(e4[0], e4[1], e4[2], e4[3]);
        }
    }

    // In-block reduction across 16 tcc groups; alias onto lB.
    __syncthreads();
    float* redS = lB;
    float* redM = lB + 512;
    float* redG = lB + 1024;
    float* redU = lB + 1536;
    #pragma unroll
    for (int i = 0; i < 4; ++i) {
        int o = (trr * 16 + tcc) * 4 + i;
        redS[o] = psum[i];
        redM[o] = pmax[i];
        redG[o] = psig[i];
        redU[o] = (float)puv[i];
    }
    __syncthreads();
    if (tid < 32) {
        const int r = tid, trr_ = r >> 2, i_ = r & 3;
        float s = 0.0f, m = -1e30f, g = 0.0f, uvf = 0.0f;
        for (int t = 0; t < 16; ++t) {
            int o = (trr_ * 16 + t) * 4 + i_;
            s += redS[o];
            float mm = redM[o], uu = redU[o];
            if (mm > m || (mm == m && uu < uvf)) { m = mm; uvf = uu; g = redG[o]; }
        }
        const int row = row0 + r;
        ws[W_PSUM + h * NT + row] = s;
        ws[W_PMAX + h * NT + row] = m;
        ws[W_PSIG + h * NT + row] = g;
        ws[W_PUV  + h * NT + row] = uvf;
    }
}

// ---------------------------------------------------------------------------
// K3b: combine the two per-half stats -> top_weight / memory_conf, then
// rescale e -> w in place (weights output becomes final).
// ---------------------------------------------------------------------------
__global__ __launch_bounds__(256)
void k3b_combine(const float* __restrict__ ws, float* __restrict__ dout)
{
    __shared__ float rinv_s[32];
    const int tid  = threadIdx.x;
    const int row0 = blockIdx.x * 32;
    if (tid < 32) {
        const int row = row0 + tid;
        float s  = ws[W_PSUM + row] + ws[W_PSUM + NT + row];
        float m0 = ws[W_PMAX + row], m1 = ws[W_PMAX + NT + row];
        float u0 = ws[W_PUV  + row], u1 = ws[W_PUV  + NT + row];
        float g0 = ws[W_PSIG + row], g1 = ws[W_PSIG + NT + row];
        float m, uvf, g;
        if (m0 > m1 || (m0 == m1 && u0 <= u1)) { m = m0; uvf = u0; g = g0; }
        else                                   { m = m1; uvf = u1; g = g1; }
        const float inv = 1.0f / s;
        rinv_s[tid] = inv;
        const float topw = __expf(m - 2.0f) * inv;
        dout[O_TOPW + row] = topw;
        const int uvi = (int)uvf;
        float cf = topw * ws[W_CONFN + uvi] * g;
        dout[O_CONF + row] = fminf(fmaxf(cf, 0.0f), 1.0f);
    }
    __syncthreads();
    // Scale this block's 32 rows of weights: 32 * 1024 float4.
    float4* wbase = (float4*)&dout[O_W];
    for (int idx = tid; idx < 32 * 1024; idx += 256) {
        const int r = idx >> 10, g4 = idx & 1023;
        const float inv = rinv_s[r];
        float4* p = wbase + (size_t)(row0 + r) * 1024 + g4;
        float4 v = *p;
        v.x *= inv; v.y *= inv; v.z *= inv; v.w *= inv;
        *p = v;
    }
}

// ---------------------------------------------------------------------------
// K4: GEMM2/3. grid (256 row-tiles x 3 col-tiles): ct0/ct1 = delta proto cols
// 0..127 / 128..255, ct2 = signature proto (raw). Tile 32 rows x 128 cols,
// 128 threads, micro-tile 4x8 (32 FMA : 3 LDS instr), K staged in 32-chunks.
// ---------------------------------------------------------------------------
__global__ __launch_bounds__(128)
void k4_gemm23(const float* __restrict__ drp, const float* __restrict__ spr,
               float* __restrict__ dout)
{
    __shared__ float wT[32 * 36];     // [kk][r], stride 36 (16B-aligned rows)
    __shared__ float bp[32 * 128];    // [kk][col]

    const int tid  = threadIdx.x;
    const int row0 = blockIdx.x * 32;
    const int ct   = blockIdx.y;

    const float* Bsrc; int ldb; size_t obase; int ldo; int ocol;
    if (ct == 0)      { Bsrc = drp;       ldb = 256; obase = O_DELTA; ldo = 256; ocol = 0;   }
    else if (ct == 1) { Bsrc = drp + 128; ldb = 256; obase = O_DELTA; ldo = 256; ocol = 128; }
    else              { Bsrc = spr;       ldb = 128; obase = O_SIG;   ldo = 128; ocol = 0;   }

    const float* wsrc = dout + O_W;
    const int trr = tid >> 4;   // 0..7  -> rows trr*4 + i
    const int tcc = tid & 15;   // 0..15 -> cols tcc*8 + j
    float acc[4][8] = {};

    for (int kc = 0; kc < 128; ++kc) {
        __syncthreads();
        for (int idx = tid; idx < 1024; idx += 128) {
            int kk = idx & 31, r = idx >> 5;
            wT[kk * 36 + r] = wsrc[(size_t)(row0 + r) * UV + kc * 32 + kk];
        }
        for (int idx = tid; idx < 4096; idx += 128) {
            int kk = idx >> 7, cc = idx & 127;
            bp[idx] = Bsrc[(size_t)(kc * 32 + kk) * ldb + cc];
        }
        __syncthreads();
        #pragma unroll 4
        for (int kk = 0; kk < 32; ++kk) {
            const float4 a  = *(const float4*)&wT[kk * 36 + trr * 4];
            const float4 b0 = *(const float4*)&bp[kk * 128 + tcc * 8];
            const float4 b1 = *(const float4*)&bp[kk * 128 + tcc * 8 + 4];
            const float av[4] = {a.x, a.y, a.z, a.w};
            const float bv[8] = {b0.x, b0.y, b0.z, b0.w, b1.x, b1.y, b1.z, b1.w};
            #pragma unroll
            for (int i = 0; i < 4; ++i)
                #pragma unroll
                for (int j = 0; j < 8; ++j)
                    acc[i][j] = fmaf(av[i], bv[j], acc[i][j]);
        }
    }

    #pragma unroll
    for (int i = 0; i < 4; ++i) {
        const int row = row0 + trr * 4 + i;
        float* o = &dout[obase + (size_t)row * ldo + ocol + tcc * 8];
        *(float4*)o       = make_float4(acc[i][0], acc[i][1], acc[i][2], acc[i][3]);
        *(float4*)(o + 4) = make_float4(acc[i][4], acc[i][5], acc[i][6], acc[i][7]);
    }
}

// ---------------------------------------------------------------------------
extern "C" void kernel_launch(void* const* d_in, const int* in_sizes, int n_in,
                              void* d_out, int out_size, void* d_ws, size_t ws_size,
                              hipStream_t stream)
{
    const float* qu   = (const float*)d_in[0];  // [8192][64]
    const float* qb   = (const float*)d_in[1];  // [8192][64]
    const float* qsig = (const float*)d_in[2];  // [8192][128]
    const float* drp  = (const float*)d_in[3];  // [4096][256]
    const float* spr  = (const float*)d_in[4];  // [4096][128]
    const float* wm   = (const float*)d_in[5];  // [4096]
    const float* ec   = (const float*)d_in[6];  // [4096]
    float* out = (float*)d_out;
    float* ws  = (float*)d_ws;

    k1_tables<<<1, 256, 0, stream>>>(wm, ec, ws);
    k2_norm<<<3072, 256, 0, stream>>>(spr, qsig, ws);
    k3_main<<<dim3(256, 2), 128, 49152, stream>>>(qu, qb, ws, out);
    k3b_combine<<<256, 256, 0, stream>>>(ws, out);
    k4_gemm23<<<dim3(256, 3), 128, 0, stream>>>(drp, spr, out);
}

// Round 2
// 1095.127 us; speedup vs baseline: 1.5488x; 1.5488x over previous
//
#include <hip/hip_runtime.h>
#include <math.h>

// Problem constants
#define NT   8192          // N*T rows
#define UV   4096          // U*B cells
#define SDIM 128
#define LOG1EM6 -13.815510557964274f

// d_out layout (float offsets): delta[8192][256], sig[8192][128], conf[8192],
// weights[8192][4096], topw[8192]
#define O_DELTA 0
#define O_SIG   2097152
#define O_CONF  3145728
#define O_W     3153920
#define O_TOPW  36708352

// d_ws layout (float offsets)
#define W_SPNT  0              // normalized signature proto, transposed [128][4096]
#define W_QST   524288         // normalized q_sigma, transposed [128][8192]
#define W_BIAS  1572864        // 0.5*usage_n + 0.5*conf_n  [4096]
#define W_CONFN 1576960        // conf_n [4096]
#define W_VALID 1581056        // validity (write_mass>0) [4096]
#define W_PSUM  1585152        // per-half row partial sums [2][8192]
#define W_PMAX  1601536        // per-half row partial max logit [2][8192]
#define W_PSIG  1617920        // sig at partial argmax [2][8192]
#define W_PUV   1634304        // uv index (as float) at partial argmax [2][8192]
// bf16 split of protos, TRANSPOSED [384 n][4096 k] (n<256: delta cols, else sig)
#define W_PTHI  1654784        // 384*4096 ushort = 786432 floats
#define W_PTLO  2441216        // 384*4096 ushort
// total ws usage: 3227648 floats = 12.9 MB

typedef __attribute__((ext_vector_type(8))) short short8;
typedef __attribute__((ext_vector_type(4))) float floatx4;

__device__ __forceinline__ unsigned short f2bf(float x) {
    unsigned u = __builtin_bit_cast(unsigned, x);
    u = u + 0x7fffu + ((u >> 16) & 1u);          // round-to-nearest-even
    return (unsigned short)(u >> 16);
}
__device__ __forceinline__ float bf2f(unsigned short h) {
    unsigned u = ((unsigned)h) << 16;
    return __builtin_bit_cast(float, u);
}

// ---------------------------------------------------------------------------
// K1: global maxes over write_mass/ema_conf -> bias/conf/valid tables.
// ---------------------------------------------------------------------------
__global__ void k1_tables(const float* __restrict__ wm,
                          const float* __restrict__ ec,
                          float* __restrict__ ws)
{
    __shared__ float red1[256];
    __shared__ float red2[256];
    const int tid = threadIdx.x;
    float m1 = 0.0f, m2 = 0.0f;
    for (int i = tid; i < UV; i += 256) {
        m1 = fmaxf(m1, log1pf(wm[i]));
        m2 = fmaxf(m2, ec[i]);
    }
    red1[tid] = m1; red2[tid] = m2;
    __syncthreads();
    for (int s = 128; s > 0; s >>= 1) {
        if (tid < s) {
            red1[tid] = fmaxf(red1[tid], red1[tid + s]);
            red2[tid] = fmaxf(red2[tid], red2[tid + s]);
        }
        __syncthreads();
    }
    const float inv1 = 1.0f / fmaxf(red1[0], 1.0f);
    const float inv2 = 1.0f / fmaxf(red2[0], 1e-6f);
    for (int i = tid; i < UV; i += 256) {
        float w  = wm[i];
        float un = log1pf(w) * inv1;
        float cn = ec[i] * inv2;
        ws[W_BIAS  + i] = 0.5f * un + 0.5f * cn;
        ws[W_CONFN + i] = cn;
        ws[W_VALID + i] = (w > 0.0f) ? 1.0f : 0.0f;
    }
}

// ---------------------------------------------------------------------------
// K2: l2-normalize signature_proto(+1e-6) and q_sigma rows; write TRANSPOSED.
// ---------------------------------------------------------------------------
__global__ void k2_norm(const float* __restrict__ spr,
                        const float* __restrict__ qsig,
                        float* __restrict__ ws)
{
    const int wid  = blockIdx.x * 4 + (threadIdx.x >> 6);
    const int lane = threadIdx.x & 63;
    if (wid < UV) {
        const float* src = spr + (size_t)wid * SDIM;
        float a = src[lane] + 1e-6f;
        float b = src[lane + 64] + 1e-6f;
        float ss = a * a + b * b;
        for (int m = 32; m > 0; m >>= 1) ss += __shfl_xor(ss, m);
        float inv = 1.0f / fmaxf(sqrtf(ss), 1e-12f);
        ws[W_SPNT + lane * UV + wid]        = a * inv;
        ws[W_SPNT + (lane + 64) * UV + wid] = b * inv;
    } else {
        const int row = wid - UV;
        const float* src = qsig + (size_t)row * SDIM;
        float a = src[lane];
        float b = src[lane + 64];
        float ss = a * a + b * b;
        for (int m = 32; m > 0; m >>= 1) ss += __shfl_xor(ss, m);
        float inv = 1.0f / fmaxf(sqrtf(ss), 1e-12f);
        ws[W_QST + lane * NT + row]        = a * inv;
        ws[W_QST + (lane + 64) * NT + row] = b * inv;
    }
}

// ---------------------------------------------------------------------------
// K2b: transpose protos into [n][k] layout and split into bf16 hi/lo pairs.
// n in [0,256): delta_rule_proto col; n in [256,384): signature_proto col.
// ---------------------------------------------------------------------------
__global__ __launch_bounds__(256)
void k2b_protoT(const float* __restrict__ drp, const float* __restrict__ spr,
                float* __restrict__ ws)
{
    __shared__ float tile[32][33];
    const int tid = threadIdx.x;
    const int k0 = blockIdx.x * 32;           // 128 blocks
    const int n0 = blockIdx.y * 32;           // 12 blocks
    {
        const int kr = tid >> 3, nc = (tid & 7) * 4;
        const int n = n0 + nc;
        float4 v;
        if (n < 256) v = *(const float4*)&drp[(size_t)(k0 + kr) * 256 + n];
        else         v = *(const float4*)&spr[(size_t)(k0 + kr) * 128 + (n - 256)];
        tile[kr][nc] = v.x; tile[kr][nc + 1] = v.y;
        tile[kr][nc + 2] = v.z; tile[kr][nc + 3] = v.w;
    }
    __syncthreads();
    {
        const int nr = tid >> 3, kc = (tid & 7) * 4;
        unsigned short* pth = (unsigned short*)(ws + W_PTHI);
        unsigned short* ptl = (unsigned short*)(ws + W_PTLO);
        ushort4 h, l;
        float x;
        x = tile[kc + 0][nr]; h.x = f2bf(x); l.x = f2bf(x - bf2f(h.x));
        x = tile[kc + 1][nr]; h.y = f2bf(x); l.y = f2bf(x - bf2f(h.y));
        x = tile[kc + 2][nr]; h.z = f2bf(x); l.z = f2bf(x - bf2f(h.z));
        x = tile[kc + 3][nr]; h.w = f2bf(x); l.w = f2bf(x - bf2f(h.w));
        *(ushort4*)&pth[(size_t)(n0 + nr) * 4096 + k0 + kc] = h;
        *(ushort4*)&ptl[(size_t)(n0 + nr) * 4096 + k0 + kc] = l;
    }
}

// ---------------------------------------------------------------------------
// K3: GEMM1 (qs . spn^T) fused with logits + fixed-shift exp. (unchanged)
// ---------------------------------------------------------------------------
__global__ __launch_bounds__(128)
void k3_main(const float* __restrict__ qu, const float* __restrict__ qb,
             float* __restrict__ ws, float* __restrict__ dout)
{
    extern __shared__ float smem[];
    float* lA = smem;          // qsT chunk [128 s][32 r]
    float* lB = smem + 4096;   // spnT chunk [128 s][64 j]

    const int tid  = threadIdx.x;
    const int row0 = blockIdx.x * 32;
    const int h    = blockIdx.y;
    const float* qsT   = ws + W_QST;
    const float* spnT  = ws + W_SPNT;
    const float* bias  = ws + W_BIAS;
    const float* validf= ws + W_VALID;
    float* wout = dout + O_W;

    for (int idx = tid; idx < 128 * 32; idx += 128) {
        int s = idx >> 5, r = idx & 31;
        lA[idx] = qsT[s * NT + row0 + r];
    }

    const int trr = tid >> 4;
    const int tcc = tid & 15;
    float psum[4] = {0, 0, 0, 0};
    float pmax[4] = {-1e30f, -1e30f, -1e30f, -1e30f};
    float psig[4] = {0, 0, 0, 0};
    unsigned puv[4] = {0, 0, 0, 0};

    for (int c = h * 32; c < h * 32 + 32; ++c) {
        __syncthreads();
        for (int idx = tid; idx < 128 * 64; idx += 128) {
            int s = idx >> 6, j = idx & 63;
            lB[idx] = spnT[s * UV + c * 64 + j];
        }
        __syncthreads();

        float acc[4][4] = {{0,0,0,0},{0,0,0,0},{0,0,0,0},{0,0,0,0}};
        #pragma unroll 8
        for (int s = 0; s < 128; ++s) {
            const float4 a = *(const float4*)&lA[s * 32 + trr * 4];
            const float4 b = *(const float4*)&lB[s * 64 + tcc * 4];
            acc[0][0] = fmaf(a.x, b.x, acc[0][0]);
            acc[0][1] = fmaf(a.x, b.y, acc[0][1]);
            acc[0][2] = fmaf(a.x, b.z, acc[0][2]);
            acc[0][3] = fmaf(a.x, b.w, acc[0][3]);
            acc[1][0] = fmaf(a.y, b.x, acc[1][0]);
            acc[1][1] = fmaf(a.y, b.y, acc[1][1]);
            acc[1][2] = fmaf(a.y, b.z, acc[1][2]);
            acc[1][3] = fmaf(a.y, b.w, acc[1][3]);
            acc[2][0] = fmaf(a.z, b.x, acc[2][0]);
            acc[2][1] = fmaf(a.z, b.y, acc[2][1]);
            acc[2][2] = fmaf(a.z, b.z, acc[2][2]);
            acc[2][3] = fmaf(a.z, b.w, acc[2][3]);
            acc[3][0] = fmaf(a.w, b.x, acc[3][0]);
            acc[3][1] = fmaf(a.w, b.y, acc[3][1]);
            acc[3][2] = fmaf(a.w, b.z, acc[3][2]);
            acc[3][3] = fmaf(a.w, b.w, acc[3][3]);
        }

        const int u = c;
        const float4 b4 = *(const float4*)&bias[c * 64 + tcc * 4];
        const float4 v4 = *(const float4*)&validf[c * 64 + tcc * 4];
        const float bl[4] = {b4.x, b4.y, b4.z, b4.w};
        const float vl[4] = {v4.x, v4.y, v4.z, v4.w};
        #pragma unroll
        for (int i = 0; i < 4; ++i) {
            const int row = row0 + trr * 4 + i;
            const float lqu = __logf(qu[(size_t)row * 64 + u]);
            const float4 qb4 = *(const float4*)&qb[(size_t)row * 64 + tcc * 4];
            const float qbl[4] = {qb4.x, qb4.y, qb4.z, qb4.w};
            float e4[4];
            #pragma unroll
            for (int j = 0; j < 4; ++j) {
                float jl  = fmaxf(lqu + __logf(qbl[j]), LOG1EM6);
                float sig = fmaf(0.5f, acc[i][j], 0.5f);
                float lg  = jl + bl[j] + sig;
                bool  vd  = vl[j] > 0.0f;
                float e   = vd ? __expf(lg - 2.0f) : 0.0f;
                e4[j] = e;
                psum[i] += e;
                if (vd && lg > pmax[i]) {
                    pmax[i] = lg;
                    puv[i]  = (unsigned)(c * 64 + tcc * 4 + j);
                    psig[i] = sig;
                }
            }
            *(float4*)&wout[(size_t)row * UV + c * 64 + tcc * 4] =
                make_float4(e4[0], e4[1], e4[2], e4[3]);
        }
    }

    __syncthreads();
    float* redS = lB;
    float* redM = lB + 512;
    float* redG = lB + 1024;
    float* redU = lB + 1536;
    #pragma unroll
    for (int i = 0; i < 4; ++i) {
        int o = (trr * 16 + tcc) * 4 + i;
        redS[o] = psum[i];
        redM[o] = pmax[i];
        redG[o] = psig[i];
        redU[o] = (float)puv[i];
    }
    __syncthreads();
    if (tid < 32) {
        const int r = tid, trr_ = r >> 2, i_ = r & 3;
        float s = 0.0f, m = -1e30f, g = 0.0f, uvf = 0.0f;
        for (int t = 0; t < 16; ++t) {
            int o = (trr_ * 16 + t) * 4 + i_;
            s += redS[o];
            float mm = redM[o], uu = redU[o];
            if (mm > m || (mm == m && uu < uvf)) { m = mm; uvf = uu; g = redG[o]; }
        }
        const int row = row0 + r;
        ws[W_PSUM + h * NT + row] = s;
        ws[W_PMAX + h * NT + row] = m;
        ws[W_PSIG + h * NT + row] = g;
        ws[W_PUV  + h * NT + row] = uvf;
    }
}

// ---------------------------------------------------------------------------
// K3b: combine halves -> top_weight/conf, rescale e -> w in place. (unchanged)
// ---------------------------------------------------------------------------
__global__ __launch_bounds__(256)
void k3b_combine(const float* __restrict__ ws, float* __restrict__ dout)
{
    __shared__ float rinv_s[32];
    const int tid  = threadIdx.x;
    const int row0 = blockIdx.x * 32;
    if (tid < 32) {
        const int row = row0 + tid;
        float s  = ws[W_PSUM + row] + ws[W_PSUM + NT + row];
        float m0 = ws[W_PMAX + row], m1 = ws[W_PMAX + NT + row];
        float u0 = ws[W_PUV  + row], u1 = ws[W_PUV  + NT + row];
        float g0 = ws[W_PSIG + row], g1 = ws[W_PSIG + NT + row];
        float m, uvf, g;
        if (m0 > m1 || (m0 == m1 && u0 <= u1)) { m = m0; uvf = u0; g = g0; }
        else                                   { m = m1; uvf = u1; g = g1; }
        const float inv = 1.0f / s;
        rinv_s[tid] = inv;
        const float topw = __expf(m - 2.0f) * inv;
        dout[O_TOPW + row] = topw;
        const int uvi = (int)uvf;
        float cf = topw * ws[W_CONFN + uvi] * g;
        dout[O_CONF + row] = fminf(fmaxf(cf, 0.0f), 1.0f);
    }
    __syncthreads();
    float4* wbase = (float4*)&dout[O_W];
    for (int idx = tid; idx < 32 * 1024; idx += 256) {
        const int r = idx >> 10, g4 = idx & 1023;
        const float inv = rinv_s[r];
        float4* p = wbase + (size_t)(row0 + r) * 1024 + g4;
        float4 v = *p;
        v.x *= inv; v.y *= inv; v.z *= inv; v.w *= inv;
        *p = v;
    }
}

// ---------------------------------------------------------------------------
// K4: MFMA GEMM, 3-term bf16 split (W_hi*P_hi + W_hi*P_lo + W_lo*P_hi).
// C[8192][384] = W[8192][4096] * P[4096][384].  BM=64 BN=192 BK=32,
// 256 threads (4 waves, 2x2), grid (128,2). W split on the fly from fp32;
// P pre-split/transposed in ws. LDS rows padded to 40 bf16 (80 B) so frag
// ds_read_b128 is 2-way (free). Chunk k+1 loads issued after the compute
// barrier -> HBM latency overlaps the MFMA section.
// ---------------------------------------------------------------------------
#define SA 40   // LDS row stride in bf16 elements

__global__ __launch_bounds__(256)
void k4_mfma(const float* __restrict__ ws_c, float* __restrict__ dout)
{
    __shared__ unsigned short sAh[64 * SA];
    __shared__ unsigned short sAl[64 * SA];
    __shared__ unsigned short sBh[192 * SA];
    __shared__ unsigned short sBl[192 * SA];

    const int tid  = threadIdx.x;
    const int row0 = blockIdx.x * 64;
    const int n0g  = blockIdx.y * 192;

    const float* wsrc = dout + O_W;
    const unsigned short* pth = (const unsigned short*)(ws_c + W_PTHI);
    const unsigned short* ptl = (const unsigned short*)(ws_c + W_PTLO);

    // staging maps
    const int ar  = tid >> 3;            // A: rows (two passes: ar, ar+32)
    const int akg = tid & 7;             //    k-group of 4 floats
    const int bn  = tid >> 2;            // B: n (three passes: bn, +64, +128)
    const int bkg = tid & 3;             //    k-group of 8 bf16

    float4 ap[2];
    uint4  bh[3], bl[3];

    // load chunk 0
    {
        const int kc = 0;
        #pragma unroll
        for (int s = 0; s < 2; ++s)
            ap[s] = *(const float4*)&wsrc[(size_t)(row0 + ar + s * 32) * UV + kc * 32 + akg * 4];
        #pragma unroll
        for (int p = 0; p < 3; ++p) {
            const size_t bo = (size_t)(n0g + bn + p * 64) * UV + kc * 32 + bkg * 8;
            bh[p] = *(const uint4*)&pth[bo];
            bl[p] = *(const uint4*)&ptl[bo];
        }
    }

    // wave/frag indices
    const int lane = tid & 63;
    const int wid  = tid >> 6;
    const int wm   = wid & 1;            // wave row 0..1 (32 rows each)
    const int wn   = wid >> 1;           // wave col 0..1 (96 cols each)
    const int fr   = lane & 15;
    const int fq   = lane >> 4;
    const int ako  = fq * 8;

    floatx4 acc[2][6];
    #pragma unroll
    for (int mt = 0; mt < 2; ++mt)
        #pragma unroll
        for (int nt = 0; nt < 6; ++nt)
            acc[mt][nt] = (floatx4){0.f, 0.f, 0.f, 0.f};

    for (int kc = 0; kc < 128; ++kc) {
        __syncthreads();                 // LDS from prev chunk fully consumed
        // A: fp32 -> bf16 hi/lo, write LDS
        #pragma unroll
        for (int s = 0; s < 2; ++s) {
            const float xs[4] = {ap[s].x, ap[s].y, ap[s].z, ap[s].w};
            ushort4 h, l;
            h.x = f2bf(xs[0]); l.x = f2bf(xs[0] - bf2f(h.x));
            h.y = f2bf(xs[1]); l.y = f2bf(xs[1] - bf2f(h.y));
            h.z = f2bf(xs[2]); l.z = f2bf(xs[2] - bf2f(h.z));
            h.w = f2bf(xs[3]); l.w = f2bf(xs[3] - bf2f(h.w));
            const int r = ar + s * 32;
            *(ushort4*)&sAh[r * SA + akg * 4] = h;
            *(ushort4*)&sAl[r * SA + akg * 4] = l;
        }
        // B: straight copy of bf16 pairs
        #pragma unroll
        for (int p = 0; p < 3; ++p) {
            const int n = bn + p * 64;
            *(uint4*)&sBh[n * SA + bkg * 8] = bh[p];
            *(uint4*)&sBl[n * SA + bkg * 8] = bl[p];
        }
        __syncthreads();

        // prefetch next chunk (overlaps with compute below)
        if (kc + 1 < 128) {
            const int kn = kc + 1;
            #pragma unroll
            for (int s = 0; s < 2; ++s)
                ap[s] = *(const float4*)&wsrc[(size_t)(row0 + ar + s * 32) * UV + kn * 32 + akg * 4];
            #pragma unroll
            for (int p = 0; p < 3; ++p) {
                const size_t bo = (size_t)(n0g + bn + p * 64) * UV + kn * 32 + bkg * 8;
                bh[p] = *(const uint4*)&pth[bo];
                bl[p] = *(const uint4*)&ptl[bo];
            }
        }

        // fragments
        short8 afh[2], afl[2], bfh[6], bfl[6];
        #pragma unroll
        for (int mt = 0; mt < 2; ++mt) {
            const int m = wm * 32 + mt * 16 + fr;
            afh[mt] = *(const short8*)&sAh[m * SA + ako];
            afl[mt] = *(const short8*)&sAl[m * SA + ako];
        }
        #pragma unroll
        for (int nt = 0; nt < 6; ++nt) {
            const int n = wn * 96 + nt * 16 + fr;
            bfh[nt] = *(const short8*)&sBh[n * SA + ako];
            bfl[nt] = *(const short8*)&sBl[n * SA + ako];
        }
        #pragma unroll
        for (int mt = 0; mt < 2; ++mt)
            #pragma unroll
            for (int nt = 0; nt < 6; ++nt) {
                acc[mt][nt] = __builtin_amdgcn_mfma_f32_16x16x32_bf16(
                    afh[mt], bfh[nt], acc[mt][nt], 0, 0, 0);
                acc[mt][nt] = __builtin_amdgcn_mfma_f32_16x16x32_bf16(
                    afh[mt], bfl[nt], acc[mt][nt], 0, 0, 0);
                acc[mt][nt] = __builtin_amdgcn_mfma_f32_16x16x32_bf16(
                    afl[mt], bfh[nt], acc[mt][nt], 0, 0, 0);
            }
    }

    // epilogue: C/D layout col=lane&15, row=(lane>>4)*4+reg
    #pragma unroll
    for (int mt = 0; mt < 2; ++mt) {
        #pragma unroll
        for (int nt = 0; nt < 6; ++nt) {
            const int gr0 = row0 + wm * 32 + mt * 16 + fq * 4;
            const int gc  = n0g + wn * 96 + nt * 16 + fr;
            const floatx4 a = acc[mt][nt];
            if (gc < 256) {
                float* o = dout + O_DELTA;
                o[(size_t)(gr0 + 0) * 256 + gc] = a[0];
                o[(size_t)(gr0 + 1) * 256 + gc] = a[1];
                o[(size_t)(gr0 + 2) * 256 + gc] = a[2];
                o[(size_t)(gr0 + 3) * 256 + gc] = a[3];
            } else {
                float* o = dout + O_SIG;
                const int c = gc - 256;
                o[(size_t)(gr0 + 0) * 128 + c] = a[0];
                o[(size_t)(gr0 + 1) * 128 + c] = a[1];
                o[(size_t)(gr0 + 2) * 128 + c] = a[2];
                o[(size_t)(gr0 + 3) * 128 + c] = a[3];
            }
        }
    }
}

// ---------------------------------------------------------------------------
extern "C" void kernel_launch(void* const* d_in, const int* in_sizes, int n_in,
                              void* d_out, int out_size, void* d_ws, size_t ws_size,
                              hipStream_t stream)
{
    const float* qu   = (const float*)d_in[0];
    const float* qb   = (const float*)d_in[1];
    const float* qsig = (const float*)d_in[2];
    const float* drp  = (const float*)d_in[3];
    const float* spr  = (const float*)d_in[4];
    const float* wm   = (const float*)d_in[5];
    const float* ec   = (const float*)d_in[6];
    float* out = (float*)d_out;
    float* ws  = (float*)d_ws;

    k1_tables<<<1, 256, 0, stream>>>(wm, ec, ws);
    k2_norm<<<3072, 256, 0, stream>>>(spr, qsig, ws);
    k2b_protoT<<<dim3(128, 12), 256, 0, stream>>>(drp, spr, ws);
    k3_main<<<dim3(256, 2), 128, 49152, stream>>>(qu, qb, ws, out);
    k3b_combine<<<256, 256, 0, stream>>>(ws, out);
    k4_mfma<<<dim3(128, 2), 256, 0, stream>>>(ws, out);
}

// Round 3
// 644.807 us; speedup vs baseline: 2.6305x; 1.6984x over previous
//
#include <hip/hip_runtime.h>
#include <math.h>

// Problem constants
#define NT   8192          // N*T rows
#define UV   4096          // U*B cells
#define SDIM 128
#define LOG1EM6 -13.815510557964274f

// d_out layout (float offsets): delta[8192][256], sig[8192][128], conf[8192],
// weights[8192][4096], topw[8192]
#define O_DELTA 0
#define O_SIG   2097152
#define O_CONF  3145728
#define O_W     3153920
#define O_TOPW  36708352

// d_ws layout (float offsets)
#define W_QSHI  0              // qs normalized, bf16 hi [8192][128] ushort
#define W_QSLO  524288
#define W_SPHI  1048576        // spn normalized, bf16 hi [4096][128] ushort
#define W_SPLO  1310720
#define W_LQU   1572864        // log(q_u) [8192][64]
#define W_LQB   2097152        // log(q_b) [8192][64]
#define W_BIAS  2621440        // 0.5*usage_n + 0.5*conf_n [4096]
#define W_CONFN 2625536        // conf_n [4096]
#define W_VALID 2629632        // validity [4096]
#define W_PSUM  2633728        // per-colblock row partials [32][8192]
#define W_PMAX  2895872
#define W_PSIG  3158016
#define W_PUV   3420160
#define W_RINV  3682304        // 1/rowsum [8192]
#define W_PTHI  3690496        // proto split bf16 hi, [384 n][4096 k] ushort
#define W_PTLO  4476928
// total ws usage: 5263360 floats = 21.1 MB

typedef __attribute__((ext_vector_type(8))) short short8;
typedef __attribute__((ext_vector_type(4))) float floatx4;

__device__ __forceinline__ unsigned short f2bf(float x) {
    unsigned u = __builtin_bit_cast(unsigned, x);
    u = u + 0x7fffu + ((u >> 16) & 1u);          // round-to-nearest-even
    return (unsigned short)(u >> 16);
}
__device__ __forceinline__ float bf2f(unsigned short h) {
    unsigned u = ((unsigned)h) << 16;
    return __builtin_bit_cast(float, u);
}

// ---------------------------------------------------------------------------
// K1: global maxes over write_mass/ema_conf -> bias/conf/valid tables.
// ---------------------------------------------------------------------------
__global__ void k1_tables(const float* __restrict__ wm,
                          const float* __restrict__ ec,
                          float* __restrict__ ws)
{
    __shared__ float red1[256];
    __shared__ float red2[256];
    const int tid = threadIdx.x;
    float m1 = 0.0f, m2 = 0.0f;
    for (int i = tid; i < UV; i += 256) {
        m1 = fmaxf(m1, log1pf(wm[i]));
        m2 = fmaxf(m2, ec[i]);
    }
    red1[tid] = m1; red2[tid] = m2;
    __syncthreads();
    for (int s = 128; s > 0; s >>= 1) {
        if (tid < s) {
            red1[tid] = fmaxf(red1[tid], red1[tid + s]);
            red2[tid] = fmaxf(red2[tid], red2[tid + s]);
        }
        __syncthreads();
    }
    const float inv1 = 1.0f / fmaxf(red1[0], 1.0f);
    const float inv2 = 1.0f / fmaxf(red2[0], 1e-6f);
    for (int i = tid; i < UV; i += 256) {
        float w  = wm[i];
        float un = log1pf(w) * inv1;
        float cn = ec[i] * inv2;
        ws[W_BIAS  + i] = 0.5f * un + 0.5f * cn;
        ws[W_CONFN + i] = cn;
        ws[W_VALID + i] = (w > 0.0f) ? 1.0f : 0.0f;
    }
}

// ---------------------------------------------------------------------------
// K2: l2-normalize signature_proto(+1e-6) and q_sigma rows; emit bf16 hi/lo
// (k-contiguous) for the MFMA GEMM1. One 64-lane wave per row.
// ---------------------------------------------------------------------------
__global__ void k2_norm(const float* __restrict__ spr,
                        const float* __restrict__ qsig,
                        float* __restrict__ ws)
{
    const int wid  = blockIdx.x * 4 + (threadIdx.x >> 6);   // 0..12287
    const int lane = threadIdx.x & 63;
    if (wid < UV) {
        const float* src = spr + (size_t)wid * SDIM;
        float a = src[lane] + 1e-6f;
        float b = src[lane + 64] + 1e-6f;
        float ss = a * a + b * b;
        for (int m = 32; m > 0; m >>= 1) ss += __shfl_xor(ss, m);
        float inv = 1.0f / fmaxf(sqrtf(ss), 1e-12f);
        a *= inv; b *= inv;
        unsigned short* hi = (unsigned short*)(ws + W_SPHI);
        unsigned short* lo = (unsigned short*)(ws + W_SPLO);
        unsigned short ha = f2bf(a), hb = f2bf(b);
        hi[wid * 128 + lane]      = ha;
        hi[wid * 128 + lane + 64] = hb;
        lo[wid * 128 + lane]      = f2bf(a - bf2f(ha));
        lo[wid * 128 + lane + 64] = f2bf(b - bf2f(hb));
    } else {
        const int row = wid - UV;
        const float* src = qsig + (size_t)row * SDIM;
        float a = src[lane];
        float b = src[lane + 64];
        float ss = a * a + b * b;
        for (int m = 32; m > 0; m >>= 1) ss += __shfl_xor(ss, m);
        float inv = 1.0f / fmaxf(sqrtf(ss), 1e-12f);
        a *= inv; b *= inv;
        unsigned short* hi = (unsigned short*)(ws + W_QSHI);
        unsigned short* lo = (unsigned short*)(ws + W_QSLO);
        unsigned short ha = f2bf(a), hb = f2bf(b);
        hi[row * 128 + lane]      = ha;
        hi[row * 128 + lane + 64] = hb;
        lo[row * 128 + lane]      = f2bf(a - bf2f(ha));
        lo[row * 128 + lane + 64] = f2bf(b - bf2f(hb));
    }
}

// ---------------------------------------------------------------------------
// K2b: transpose protos into [n][k] layout and split into bf16 hi/lo pairs.
// ---------------------------------------------------------------------------
__global__ __launch_bounds__(256)
void k2b_protoT(const float* __restrict__ drp, const float* __restrict__ spr,
                float* __restrict__ ws)
{
    __shared__ float tile[32][33];
    const int tid = threadIdx.x;
    const int k0 = blockIdx.x * 32;
    const int n0 = blockIdx.y * 32;
    {
        const int kr = tid >> 3, nc = (tid & 7) * 4;
        const int n = n0 + nc;
        float4 v;
        if (n < 256) v = *(const float4*)&drp[(size_t)(k0 + kr) * 256 + n];
        else         v = *(const float4*)&spr[(size_t)(k0 + kr) * 128 + (n - 256)];
        tile[kr][nc] = v.x; tile[kr][nc + 1] = v.y;
        tile[kr][nc + 2] = v.z; tile[kr][nc + 3] = v.w;
    }
    __syncthreads();
    {
        const int nr = tid >> 3, kc = (tid & 7) * 4;
        unsigned short* pth = (unsigned short*)(ws + W_PTHI);
        unsigned short* ptl = (unsigned short*)(ws + W_PTLO);
        ushort4 h, l;
        float x;
        x = tile[kc + 0][nr]; h.x = f2bf(x); l.x = f2bf(x - bf2f(h.x));
        x = tile[kc + 1][nr]; h.y = f2bf(x); l.y = f2bf(x - bf2f(h.y));
        x = tile[kc + 2][nr]; h.z = f2bf(x); l.z = f2bf(x - bf2f(h.z));
        x = tile[kc + 3][nr]; h.w = f2bf(x); l.w = f2bf(x - bf2f(h.w));
        *(ushort4*)&pth[(size_t)(n0 + nr) * 4096 + k0 + kc] = h;
        *(ushort4*)&ptl[(size_t)(n0 + nr) * 4096 + k0 + kc] = l;
    }
}

// ---------------------------------------------------------------------------
// K2c: log tables for q_u / q_b: lqu[row][64], lqb[row][64].
// ---------------------------------------------------------------------------
__global__ __launch_bounds__(256)
void k2c_logs(const float* __restrict__ qu, const float* __restrict__ qb,
              float* __restrict__ ws)
{
    const int t = blockIdx.x * 256 + threadIdx.x;           // 512 blocks
    const float* src = blockIdx.y ? qb : qu;
    float* dst = ws + (blockIdx.y ? W_LQB : W_LQU);
    float4 v = *(const float4*)&src[t * 4];
    v.x = __logf(v.x); v.y = __logf(v.y);
    v.z = __logf(v.z); v.w = __logf(v.w);
    *(float4*)&dst[t * 4] = v;
}

// ---------------------------------------------------------------------------
// K3: MFMA GEMM1 (qs . spn^T, 3-term bf16 split) fused with logits + exp +
// per-row partial stats. BM=64 BN=128 BK=32 (K=128, 4 chunks), 256 threads
// (2x2 waves), grid (128 row-tiles, 32 col-blocks) = 4096 blocks.
// ---------------------------------------------------------------------------
#define SA3 40

__global__ __launch_bounds__(256)
void k3_mfma(float* __restrict__ ws, float* __restrict__ dout)
{
    __shared__ unsigned short sAh[64 * SA3];
    __shared__ unsigned short sAl[64 * SA3];
    __shared__ unsigned short sBh[128 * SA3];
    __shared__ unsigned short sBl[128 * SA3];
    __shared__ float sS[2][64], sM[2][64], sG[2][64], sU[2][64];

    const int tid  = threadIdx.x;
    const int row0 = blockIdx.x * 64;
    const int cb   = blockIdx.y;
    const int n0   = cb * 128;

    const unsigned short* qsh = (const unsigned short*)(ws + W_QSHI);
    const unsigned short* qsl = (const unsigned short*)(ws + W_QSLO);
    const unsigned short* sph = (const unsigned short*)(ws + W_SPHI);
    const unsigned short* spl = (const unsigned short*)(ws + W_SPLO);

    // staging maps
    const int tAr = tid >> 2;            // 0..63 rows
    const int tAk = (tid & 3) * 8;       // k-group of 8 ushorts
    const int tBn = tid >> 2;            // B cols (two passes: tBn, tBn+64)
    const int tBk = (tid & 3) * 8;

    uint4 pah, pal, pbh[2], pbl[2];
    {
        pah = *(const uint4*)&qsh[(size_t)(row0 + tAr) * 128 + tAk];
        pal = *(const uint4*)&qsl[(size_t)(row0 + tAr) * 128 + tAk];
        #pragma unroll
        for (int p = 0; p < 2; ++p) {
            pbh[p] = *(const uint4*)&sph[(size_t)(n0 + tBn + p * 64) * 128 + tBk];
            pbl[p] = *(const uint4*)&spl[(size_t)(n0 + tBn + p * 64) * 128 + tBk];
        }
    }

    const int lane = tid & 63;
    const int wid  = tid >> 6;
    const int wm   = wid & 1;            // row half (32 rows)
    const int wn   = wid >> 1;           // col half (64 cols)
    const int fr   = lane & 15;
    const int fq   = lane >> 4;
    const int ako  = fq * 8;

    floatx4 acc[2][4];
    #pragma unroll
    for (int mt = 0; mt < 2; ++mt)
        #pragma unroll
        for (int nt = 0; nt < 4; ++nt)
            acc[mt][nt] = (floatx4){0.f, 0.f, 0.f, 0.f};

    for (int kc = 0; kc < 4; ++kc) {
        __syncthreads();
        *(uint4*)&sAh[tAr * SA3 + tAk] = pah;
        *(uint4*)&sAl[tAr * SA3 + tAk] = pal;
        #pragma unroll
        for (int p = 0; p < 2; ++p) {
            *(uint4*)&sBh[(tBn + p * 64) * SA3 + tBk] = pbh[p];
            *(uint4*)&sBl[(tBn + p * 64) * SA3 + tBk] = pbl[p];
        }
        __syncthreads();

        if (kc < 3) {
            const int kn = (kc + 1) * 32;
            pah = *(const uint4*)&qsh[(size_t)(row0 + tAr) * 128 + kn + tAk];
            pal = *(const uint4*)&qsl[(size_t)(row0 + tAr) * 128 + kn + tAk];
            #pragma unroll
            for (int p = 0; p < 2; ++p) {
                pbh[p] = *(const uint4*)&sph[(size_t)(n0 + tBn + p * 64) * 128 + kn + tBk];
                pbl[p] = *(const uint4*)&spl[(size_t)(n0 + tBn + p * 64) * 128 + kn + tBk];
            }
        }

        short8 afh[2], afl[2], bfh[4], bfl[4];
        #pragma unroll
        for (int mt = 0; mt < 2; ++mt) {
            const int m = wm * 32 + mt * 16 + fr;
            afh[mt] = *(const short8*)&sAh[m * SA3 + ako];
            afl[mt] = *(const short8*)&sAl[m * SA3 + ako];
        }
        #pragma unroll
        for (int nt = 0; nt < 4; ++nt) {
            const int n = wn * 64 + nt * 16 + fr;
            bfh[nt] = *(const short8*)&sBh[n * SA3 + ako];
            bfl[nt] = *(const short8*)&sBl[n * SA3 + ako];
        }
        #pragma unroll
        for (int mt = 0; mt < 2; ++mt)
            #pragma unroll
            for (int nt = 0; nt < 4; ++nt) {
                acc[mt][nt] = __builtin_amdgcn_mfma_f32_16x16x32_bf16(
                    afh[mt], bfh[nt], acc[mt][nt], 0, 0, 0);
                acc[mt][nt] = __builtin_amdgcn_mfma_f32_16x16x32_bf16(
                    afh[mt], bfl[nt], acc[mt][nt], 0, 0, 0);
                acc[mt][nt] = __builtin_amdgcn_mfma_f32_16x16x32_bf16(
                    afl[mt], bfh[nt], acc[mt][nt], 0, 0, 0);
            }
    }

    // --- epilogue: logits -> e (unnormalized), partial row stats -----------
    const float* lqu    = ws + W_LQU;
    const float* lqb    = ws + W_LQB;
    const float* bias   = ws + W_BIAS;
    const float* validf = ws + W_VALID;
    float* wout = dout + O_W;

    float ps[2][4], pm[2][4], pg[2][4], pu[2][4];
    #pragma unroll
    for (int mt = 0; mt < 2; ++mt)
        #pragma unroll
        for (int r = 0; r < 4; ++r) {
            ps[mt][r] = 0.f; pm[mt][r] = -1e30f; pg[mt][r] = 0.f; pu[mt][r] = 0.f;
        }

    #pragma unroll
    for (int mt = 0; mt < 2; ++mt) {
        const int rbase = row0 + wm * 32 + mt * 16 + fq * 4;
        #pragma unroll
        for (int nt = 0; nt < 4; ++nt) {
            const int uvb = n0 + wn * 64 + nt * 16;
            const int u   = uvb >> 6;
            const int uv  = uvb + fr;
            const int v   = uv & 63;
            const float bv = bias[uv];
            const float vd = validf[uv];
            const floatx4 a = acc[mt][nt];
            #pragma unroll
            for (int reg = 0; reg < 4; ++reg) {
                const int row = rbase + reg;
                const float jl  = fmaxf(lqu[(row << 6) + u] + lqb[(row << 6) + v], LOG1EM6);
                const float sig = fmaf(0.5f, a[reg], 0.5f);
                const float lg  = jl + bv + sig;
                const float e   = (vd > 0.f) ? __expf(lg - 2.f) : 0.f;
                wout[((size_t)row << 12) + uv] = e;
                ps[mt][reg] += e;
                if (vd > 0.f && lg > pm[mt][reg]) {
                    pm[mt][reg] = lg; pu[mt][reg] = (float)uv; pg[mt][reg] = sig;
                }
            }
        }
    }

    // reduce across the 16-lane fr group
    #pragma unroll
    for (int off = 1; off < 16; off <<= 1) {
        #pragma unroll
        for (int mt = 0; mt < 2; ++mt)
            #pragma unroll
            for (int r = 0; r < 4; ++r) {
                ps[mt][r] += __shfl_xor(ps[mt][r], off);
                float om = __shfl_xor(pm[mt][r], off);
                float ou = __shfl_xor(pu[mt][r], off);
                float og = __shfl_xor(pg[mt][r], off);
                if (om > pm[mt][r] || (om == pm[mt][r] && ou < pu[mt][r])) {
                    pm[mt][r] = om; pu[mt][r] = ou; pg[mt][r] = og;
                }
            }
    }
    if (fr == 0) {
        #pragma unroll
        for (int mt = 0; mt < 2; ++mt)
            #pragma unroll
            for (int r = 0; r < 4; ++r) {
                const int rl = wm * 32 + mt * 16 + fq * 4 + r;
                sS[wn][rl] = ps[mt][r]; sM[wn][rl] = pm[mt][r];
                sG[wn][rl] = pg[mt][r]; sU[wn][rl] = pu[mt][r];
            }
    }
    __syncthreads();
    if (tid < 64) {
        const float s  = sS[0][tid] + sS[1][tid];
        const float m0 = sM[0][tid], m1 = sM[1][tid];
        float m, uvf, g;
        if (m0 > m1 || (m0 == m1 && sU[0][tid] <= sU[1][tid])) {
            m = m0; uvf = sU[0][tid]; g = sG[0][tid];
        } else {
            m = m1; uvf = sU[1][tid]; g = sG[1][tid];
        }
        const int row = row0 + tid;
        ws[W_PSUM + cb * NT + row] = s;
        ws[W_PMAX + cb * NT + row] = m;
        ws[W_PSIG + cb * NT + row] = g;
        ws[W_PUV  + cb * NT + row] = uvf;
    }
}

// ---------------------------------------------------------------------------
// K3b: combine 32 col-block partials per row -> rinv, top_weight, conf.
// ---------------------------------------------------------------------------
__global__ __launch_bounds__(256)
void k3b_stats(float* __restrict__ ws, float* __restrict__ dout)
{
    const int row = blockIdx.x * 256 + threadIdx.x;         // 32 blocks
    float s = 0.f, m = -1e30f, uvf = 0.f, g = 0.f;
    for (int cb = 0; cb < 32; ++cb) {
        s += ws[W_PSUM + cb * NT + row];
        const float om = ws[W_PMAX + cb * NT + row];
        const float ou = ws[W_PUV  + cb * NT + row];
        const float og = ws[W_PSIG + cb * NT + row];
        if (om > m || (om == m && ou < uvf)) { m = om; uvf = ou; g = og; }
    }
    const float inv = 1.0f / s;
    ws[W_RINV + row] = inv;
    const float topw = __expf(m - 2.f) * inv;
    dout[O_TOPW + row] = topw;
    const int uvi = (int)uvf;
    const float cf = topw * ws[W_CONFN + uvi] * g;
    dout[O_CONF + row] = fminf(fmaxf(cf, 0.f), 1.f);
}

// ---------------------------------------------------------------------------
// K3c: normalize weights in place (e -> w), wide grid-strided float4 sweep.
// ---------------------------------------------------------------------------
__global__ __launch_bounds__(256)
void k3c_scale(const float* __restrict__ ws, float* __restrict__ dout)
{
    float4* wb = (float4*)(dout + O_W);
    const float* rinv = ws + W_RINV;
    const int t = blockIdx.x * 256 + threadIdx.x;           // 2048 blocks
    #pragma unroll 4
    for (int i = 0; i < 16; ++i) {
        const int idx = t + i * 524288;
        const float r = rinv[idx >> 10];
        float4 v = wb[idx];
        v.x *= r; v.y *= r; v.z *= r; v.w *= r;
        wb[idx] = v;
    }
}

// ---------------------------------------------------------------------------
// K4: MFMA GEMM2/3, 3-term bf16 split (unchanged from round 2).
// ---------------------------------------------------------------------------
#define SA 40

__global__ __launch_bounds__(256)
void k4_mfma(const float* __restrict__ ws_c, float* __restrict__ dout)
{
    __shared__ unsigned short sAh[64 * SA];
    __shared__ unsigned short sAl[64 * SA];
    __shared__ unsigned short sBh[192 * SA];
    __shared__ unsigned short sBl[192 * SA];

    const int tid  = threadIdx.x;
    const int row0 = blockIdx.x * 64;
    const int n0g  = blockIdx.y * 192;

    const float* wsrc = dout + O_W;
    const unsigned short* pth = (const unsigned short*)(ws_c + W_PTHI);
    const unsigned short* ptl = (const unsigned short*)(ws_c + W_PTLO);

    const int ar  = tid >> 3;
    const int akg = tid & 7;
    const int bn  = tid >> 2;
    const int bkg = tid & 3;

    float4 ap[2];
    uint4  bh[3], bl[3];
    {
        #pragma unroll
        for (int s = 0; s < 2; ++s)
            ap[s] = *(const float4*)&wsrc[(size_t)(row0 + ar + s * 32) * UV + akg * 4];
        #pragma unroll
        for (int p = 0; p < 3; ++p) {
            const size_t bo = (size_t)(n0g + bn + p * 64) * UV + bkg * 8;
            bh[p] = *(const uint4*)&pth[bo];
            bl[p] = *(const uint4*)&ptl[bo];
        }
    }

    const int lane = tid & 63;
    const int wid  = tid >> 6;
    const int wm   = wid & 1;
    const int wn   = wid >> 1;
    const int fr   = lane & 15;
    const int fq   = lane >> 4;
    const int ako  = fq * 8;

    floatx4 acc[2][6];
    #pragma unroll
    for (int mt = 0; mt < 2; ++mt)
        #pragma unroll
        for (int nt = 0; nt < 6; ++nt)
            acc[mt][nt] = (floatx4){0.f, 0.f, 0.f, 0.f};

    for (int kc = 0; kc < 128; ++kc) {
        __syncthreads();
        #pragma unroll
        for (int s = 0; s < 2; ++s) {
            const float xs[4] = {ap[s].x, ap[s].y, ap[s].z, ap[s].w};
            ushort4 h, l;
            h.x = f2bf(xs[0]); l.x = f2bf(xs[0] - bf2f(h.x));
            h.y = f2bf(xs[1]); l.y = f2bf(xs[1] - bf2f(h.y));
            h.z = f2bf(xs[2]); l.z = f2bf(xs[2] - bf2f(h.z));
            h.w = f2bf(xs[3]); l.w = f2bf(xs[3] - bf2f(h.w));
            const int r = ar + s * 32;
            *(ushort4*)&sAh[r * SA + akg * 4] = h;
            *(ushort4*)&sAl[r * SA + akg * 4] = l;
        }
        #pragma unroll
        for (int p = 0; p < 3; ++p) {
            const int n = bn + p * 64;
            *(uint4*)&sBh[n * SA + bkg * 8] = bh[p];
            *(uint4*)&sBl[n * SA + bkg * 8] = bl[p];
        }
        __syncthreads();

        if (kc + 1 < 128) {
            const int kn = kc + 1;
            #pragma unroll
            for (int s = 0; s < 2; ++s)
                ap[s] = *(const float4*)&wsrc[(size_t)(row0 + ar + s * 32) * UV + kn * 32 + akg * 4];
            #pragma unroll
            for (int p = 0; p < 3; ++p) {
                const size_t bo = (size_t)(n0g + bn + p * 64) * UV + kn * 32 + bkg * 8;
                bh[p] = *(const uint4*)&pth[bo];
                bl[p] = *(const uint4*)&ptl[bo];
            }
        }

        short8 afh[2], afl[2], bfh[6], bfl[6];
        #pragma unroll
        for (int mt = 0; mt < 2; ++mt) {
            const int m = wm * 32 + mt * 16 + fr;
            afh[mt] = *(const short8*)&sAh[m * SA + ako];
            afl[mt] = *(const short8*)&sAl[m * SA + ako];
        }
        #pragma unroll
        for (int nt = 0; nt < 6; ++nt) {
            const int n = wn * 96 + nt * 16 + fr;
            bfh[nt] = *(const short8*)&sBh[n * SA + ako];
            bfl[nt] = *(const short8*)&sBl[n * SA + ako];
        }
        #pragma unroll
        for (int mt = 0; mt < 2; ++mt)
            #pragma unroll
            for (int nt = 0; nt < 6; ++nt) {
                acc[mt][nt] = __builtin_amdgcn_mfma_f32_16x16x32_bf16(
                    afh[mt], bfh[nt], acc[mt][nt], 0, 0, 0);
                acc[mt][nt] = __builtin_amdgcn_mfma_f32_16x16x32_bf16(
                    afh[mt], bfl[nt], acc[mt][nt], 0, 0, 0);
                acc[mt][nt] = __builtin_amdgcn_mfma_f32_16x16x32_bf16(
                    afl[mt], bfh[nt], acc[mt][nt], 0, 0, 0);
            }
    }

    #pragma unroll
    for (int mt = 0; mt < 2; ++mt) {
        #pragma unroll
        for (int nt = 0; nt < 6; ++nt) {
            const int gr0 = row0 + wm * 32 + mt * 16 + fq * 4;
            const int gc  = n0g + wn * 96 + nt * 16 + fr;
            const floatx4 a = acc[mt][nt];
            if (gc < 256) {
                float* o = dout + O_DELTA;
                o[(size_t)(gr0 + 0) * 256 + gc] = a[0];
                o[(size_t)(gr0 + 1) * 256 + gc] = a[1];
                o[(size_t)(gr0 + 2) * 256 + gc] = a[2];
                o[(size_t)(gr0 + 3) * 256 + gc] = a[3];
            } else {
                float* o = dout + O_SIG;
                const int c = gc - 256;
                o[(size_t)(gr0 + 0) * 128 + c] = a[0];
                o[(size_t)(gr0 + 1) * 128 + c] = a[1];
                o[(size_t)(gr0 + 2) * 128 + c] = a[2];
                o[(size_t)(gr0 + 3) * 128 + c] = a[3];
            }
        }
    }
}

// ---------------------------------------------------------------------------
extern "C" void kernel_launch(void* const* d_in, const int* in_sizes, int n_in,
                              void* d_out, int out_size, void* d_ws, size_t ws_size,
                              hipStream_t stream)
{
    const float* qu   = (const float*)d_in[0];
    const float* qb   = (const float*)d_in[1];
    const float* qsig = (const float*)d_in[2];
    const float* drp  = (const float*)d_in[3];
    const float* spr  = (const float*)d_in[4];
    const float* wm   = (const float*)d_in[5];
    const float* ec   = (const float*)d_in[6];
    float* out = (float*)d_out;
    float* ws  = (float*)d_ws;

    k1_tables<<<1, 256, 0, stream>>>(wm, ec, ws);
    k2_norm<<<3072, 256, 0, stream>>>(spr, qsig, ws);
    k2b_protoT<<<dim3(128, 12), 256, 0, stream>>>(drp, spr, ws);
    k2c_logs<<<dim3(512, 2), 256, 0, stream>>>(qu, qb, ws);
    k3_mfma<<<dim3(128, 32), 256, 0, stream>>>(ws, out);
    k3b_stats<<<32, 256, 0, stream>>>(ws, out);
    k3c_scale<<<2048, 256, 0, stream>>>(ws, out);
    k4_mfma<<<dim3(128, 2), 256, 0, stream>>>(ws, out);
}

// Round 4
// 599.393 us; speedup vs baseline: 2.8298x; 1.0758x over previous
//
#include <hip/hip_runtime.h>
#include <math.h>

// Problem constants
#define NT   8192          // N*T rows
#define UV   4096          // U*B cells
#define SDIM 128
#define LOG1EM6 -13.815510557964274f

// d_out layout (float offsets): delta[8192][256], sig[8192][128], conf[8192],
// weights[8192][4096], topw[8192]
#define O_DELTA 0
#define O_SIG   2097152
#define O_CONF  3145728
#define O_W     3153920
#define O_TOPW  36708352

// d_ws layout (float offsets)
#define W_QSHI  0              // qs normalized, bf16 hi [8192][128] ushort
#define W_QSLO  524288
#define W_SPHI  1048576        // spn normalized, bf16 hi [4096][128] ushort
#define W_SPLO  1310720
#define W_LQU   1572864        // log(q_u) [8192][64]
#define W_LQB   2097152        // log(q_b) [8192][64]
#define W_BIAS  2621440        // 0.5*usage_n + 0.5*conf_n [4096]
#define W_CONFN 2625536        // conf_n [4096]
#define W_VALID 2629632        // validity [4096]
#define W_PSUM  2633728        // per-colblock row partials [32][8192]
#define W_PMAX  2895872
#define W_PSIG  3158016
#define W_PUV   3420160
#define W_RINV  3682304        // 1/rowsum [8192]
#define W_PTHI  3690496        // proto split bf16 hi, [384 n][4096 k] ushort
#define W_PTLO  4476928
// total ws usage: 5263360 floats = 21.1 MB

typedef __attribute__((ext_vector_type(8))) short short8;
typedef __attribute__((ext_vector_type(4))) float floatx4;

__device__ __forceinline__ unsigned short f2bf(float x) {
    unsigned u = __builtin_bit_cast(unsigned, x);
    u = u + 0x7fffu + ((u >> 16) & 1u);          // round-to-nearest-even
    return (unsigned short)(u >> 16);
}
__device__ __forceinline__ float bf2f(unsigned short h) {
    unsigned u = ((unsigned)h) << 16;
    return __builtin_bit_cast(float, u);
}

// ---------------------------------------------------------------------------
// K1: global maxes over write_mass/ema_conf -> bias/conf/valid tables.
// ---------------------------------------------------------------------------
__global__ void k1_tables(const float* __restrict__ wm,
                          const float* __restrict__ ec,
                          float* __restrict__ ws)
{
    __shared__ float red1[256];
    __shared__ float red2[256];
    const int tid = threadIdx.x;
    float m1 = 0.0f, m2 = 0.0f;
    for (int i = tid; i < UV; i += 256) {
        m1 = fmaxf(m1, log1pf(wm[i]));
        m2 = fmaxf(m2, ec[i]);
    }
    red1[tid] = m1; red2[tid] = m2;
    __syncthreads();
    for (int s = 128; s > 0; s >>= 1) {
        if (tid < s) {
            red1[tid] = fmaxf(red1[tid], red1[tid + s]);
            red2[tid] = fmaxf(red2[tid], red2[tid + s]);
        }
        __syncthreads();
    }
    const float inv1 = 1.0f / fmaxf(red1[0], 1.0f);
    const float inv2 = 1.0f / fmaxf(red2[0], 1e-6f);
    for (int i = tid; i < UV; i += 256) {
        float w  = wm[i];
        float un = log1pf(w) * inv1;
        float cn = ec[i] * inv2;
        ws[W_BIAS  + i] = 0.5f * un + 0.5f * cn;
        ws[W_CONFN + i] = cn;
        ws[W_VALID + i] = (w > 0.0f) ? 1.0f : 0.0f;
    }
}

// ---------------------------------------------------------------------------
// K2: l2-normalize signature_proto(+1e-6) and q_sigma rows; emit bf16 hi/lo.
// ---------------------------------------------------------------------------
__global__ void k2_norm(const float* __restrict__ spr,
                        const float* __restrict__ qsig,
                        float* __restrict__ ws)
{
    const int wid  = blockIdx.x * 4 + (threadIdx.x >> 6);   // 0..12287
    const int lane = threadIdx.x & 63;
    if (wid < UV) {
        const float* src = spr + (size_t)wid * SDIM;
        float a = src[lane] + 1e-6f;
        float b = src[lane + 64] + 1e-6f;
        float ss = a * a + b * b;
        for (int m = 32; m > 0; m >>= 1) ss += __shfl_xor(ss, m);
        float inv = 1.0f / fmaxf(sqrtf(ss), 1e-12f);
        a *= inv; b *= inv;
        unsigned short* hi = (unsigned short*)(ws + W_SPHI);
        unsigned short* lo = (unsigned short*)(ws + W_SPLO);
        unsigned short ha = f2bf(a), hb = f2bf(b);
        hi[wid * 128 + lane]      = ha;
        hi[wid * 128 + lane + 64] = hb;
        lo[wid * 128 + lane]      = f2bf(a - bf2f(ha));
        lo[wid * 128 + lane + 64] = f2bf(b - bf2f(hb));
    } else {
        const int row = wid - UV;
        const float* src = qsig + (size_t)row * SDIM;
        float a = src[lane];
        float b = src[lane + 64];
        float ss = a * a + b * b;
        for (int m = 32; m > 0; m >>= 1) ss += __shfl_xor(ss, m);
        float inv = 1.0f / fmaxf(sqrtf(ss), 1e-12f);
        a *= inv; b *= inv;
        unsigned short* hi = (unsigned short*)(ws + W_QSHI);
        unsigned short* lo = (unsigned short*)(ws + W_QSLO);
        unsigned short ha = f2bf(a), hb = f2bf(b);
        hi[row * 128 + lane]      = ha;
        hi[row * 128 + lane + 64] = hb;
        lo[row * 128 + lane]      = f2bf(a - bf2f(ha));
        lo[row * 128 + lane + 64] = f2bf(b - bf2f(hb));
    }
}

// ---------------------------------------------------------------------------
// K2b: transpose protos into [n][k] layout and split into bf16 hi/lo pairs.
// ---------------------------------------------------------------------------
__global__ __launch_bounds__(256)
void k2b_protoT(const float* __restrict__ drp, const float* __restrict__ spr,
                float* __restrict__ ws)
{
    __shared__ float tile[32][33];
    const int tid = threadIdx.x;
    const int k0 = blockIdx.x * 32;
    const int n0 = blockIdx.y * 32;
    {
        const int kr = tid >> 3, nc = (tid & 7) * 4;
        const int n = n0 + nc;
        float4 v;
        if (n < 256) v = *(const float4*)&drp[(size_t)(k0 + kr) * 256 + n];
        else         v = *(const float4*)&spr[(size_t)(k0 + kr) * 128 + (n - 256)];
        tile[kr][nc] = v.x; tile[kr][nc + 1] = v.y;
        tile[kr][nc + 2] = v.z; tile[kr][nc + 3] = v.w;
    }
    __syncthreads();
    {
        const int nr = tid >> 3, kc = (tid & 7) * 4;
        unsigned short* pth = (unsigned short*)(ws + W_PTHI);
        unsigned short* ptl = (unsigned short*)(ws + W_PTLO);
        ushort4 h, l;
        float x;
        x = tile[kc + 0][nr]; h.x = f2bf(x); l.x = f2bf(x - bf2f(h.x));
        x = tile[kc + 1][nr]; h.y = f2bf(x); l.y = f2bf(x - bf2f(h.y));
        x = tile[kc + 2][nr]; h.z = f2bf(x); l.z = f2bf(x - bf2f(h.z));
        x = tile[kc + 3][nr]; h.w = f2bf(x); l.w = f2bf(x - bf2f(h.w));
        *(ushort4*)&pth[(size_t)(n0 + nr) * 4096 + k0 + kc] = h;
        *(ushort4*)&ptl[(size_t)(n0 + nr) * 4096 + k0 + kc] = l;
    }
}

// ---------------------------------------------------------------------------
// K2c: log tables for q_u / q_b: lqu[row][64], lqb[row][64].
// ---------------------------------------------------------------------------
__global__ __launch_bounds__(256)
void k2c_logs(const float* __restrict__ qu, const float* __restrict__ qb,
              float* __restrict__ ws)
{
    const int t = blockIdx.x * 256 + threadIdx.x;           // 512 blocks
    const float* src = blockIdx.y ? qb : qu;
    float* dst = ws + (blockIdx.y ? W_LQB : W_LQU);
    float4 v = *(const float4*)&src[t * 4];
    v.x = __logf(v.x); v.y = __logf(v.y);
    v.z = __logf(v.z); v.w = __logf(v.w);
    *(float4*)&dst[t * 4] = v;
}

// ---------------------------------------------------------------------------
// K3: MFMA GEMM1 (qs . spn^T, 3-term bf16 split) fused with logits + exp +
// per-row partial stats. BM=64 BN=128 BK=32 (K=128, 4 chunks), 256 threads
// (2x2 waves), grid (128 row-tiles, 32 col-blocks). Term-major MFMA order.
// ---------------------------------------------------------------------------
#define SA3 40

__global__ __launch_bounds__(256, 4)
void k3_mfma(float* __restrict__ ws, float* __restrict__ dout)
{
    __shared__ unsigned short sAh[64 * SA3];
    __shared__ unsigned short sAl[64 * SA3];
    __shared__ unsigned short sBh[128 * SA3];
    __shared__ unsigned short sBl[128 * SA3];
    __shared__ float sS[2][64], sM[2][64], sG[2][64], sU[2][64];

    const int tid  = threadIdx.x;
    const int row0 = blockIdx.x * 64;
    const int cb   = blockIdx.y;
    const int n0   = cb * 128;

    const unsigned short* qsh = (const unsigned short*)(ws + W_QSHI);
    const unsigned short* qsl = (const unsigned short*)(ws + W_QSLO);
    const unsigned short* sph = (const unsigned short*)(ws + W_SPHI);
    const unsigned short* spl = (const unsigned short*)(ws + W_SPLO);

    const int tAr = tid >> 2;
    const int tAk = (tid & 3) * 8;
    const int tBn = tid >> 2;
    const int tBk = (tid & 3) * 8;

    uint4 pah, pal, pbh[2], pbl[2];
    {
        pah = *(const uint4*)&qsh[(size_t)(row0 + tAr) * 128 + tAk];
        pal = *(const uint4*)&qsl[(size_t)(row0 + tAr) * 128 + tAk];
        #pragma unroll
        for (int p = 0; p < 2; ++p) {
            pbh[p] = *(const uint4*)&sph[(size_t)(n0 + tBn + p * 64) * 128 + tBk];
            pbl[p] = *(const uint4*)&spl[(size_t)(n0 + tBn + p * 64) * 128 + tBk];
        }
    }

    const int lane = tid & 63;
    const int wid  = tid >> 6;
    const int wm   = wid & 1;
    const int wn   = wid >> 1;
    const int fr   = lane & 15;
    const int fq   = lane >> 4;
    const int ako  = fq * 8;

    floatx4 acc[2][4];
    #pragma unroll
    for (int mt = 0; mt < 2; ++mt)
        #pragma unroll
        for (int nt = 0; nt < 4; ++nt)
            acc[mt][nt] = (floatx4){0.f, 0.f, 0.f, 0.f};

    for (int kc = 0; kc < 4; ++kc) {
        __syncthreads();
        *(uint4*)&sAh[tAr * SA3 + tAk] = pah;
        *(uint4*)&sAl[tAr * SA3 + tAk] = pal;
        #pragma unroll
        for (int p = 0; p < 2; ++p) {
            *(uint4*)&sBh[(tBn + p * 64) * SA3 + tBk] = pbh[p];
            *(uint4*)&sBl[(tBn + p * 64) * SA3 + tBk] = pbl[p];
        }
        __syncthreads();

        if (kc < 3) {
            const int kn = (kc + 1) * 32;
            pah = *(const uint4*)&qsh[(size_t)(row0 + tAr) * 128 + kn + tAk];
            pal = *(const uint4*)&qsl[(size_t)(row0 + tAr) * 128 + kn + tAk];
            #pragma unroll
            for (int p = 0; p < 2; ++p) {
                pbh[p] = *(const uint4*)&sph[(size_t)(n0 + tBn + p * 64) * 128 + kn + tBk];
                pbl[p] = *(const uint4*)&spl[(size_t)(n0 + tBn + p * 64) * 128 + kn + tBk];
            }
        }

        short8 afh[2], afl[2], bfh[4], bfl[4];
        #pragma unroll
        for (int mt = 0; mt < 2; ++mt) {
            const int m = wm * 32 + mt * 16 + fr;
            afh[mt] = *(const short8*)&sAh[m * SA3 + ako];
            afl[mt] = *(const short8*)&sAl[m * SA3 + ako];
        }
        #pragma unroll
        for (int nt = 0; nt < 4; ++nt) {
            const int n = wn * 64 + nt * 16 + fr;
            bfh[nt] = *(const short8*)&sBh[n * SA3 + ako];
            bfl[nt] = *(const short8*)&sBl[n * SA3 + ako];
        }
        // term-major: 8 independent MFMAs back-to-back per term
        #pragma unroll
        for (int mt = 0; mt < 2; ++mt)
            #pragma unroll
            for (int nt = 0; nt < 4; ++nt)
                acc[mt][nt] = __builtin_amdgcn_mfma_f32_16x16x32_bf16(
                    afh[mt], bfh[nt], acc[mt][nt], 0, 0, 0);
        #pragma unroll
        for (int mt = 0; mt < 2; ++mt)
            #pragma unroll
            for (int nt = 0; nt < 4; ++nt)
                acc[mt][nt] = __builtin_amdgcn_mfma_f32_16x16x32_bf16(
                    afh[mt], bfl[nt], acc[mt][nt], 0, 0, 0);
        #pragma unroll
        for (int mt = 0; mt < 2; ++mt)
            #pragma unroll
            for (int nt = 0; nt < 4; ++nt)
                acc[mt][nt] = __builtin_amdgcn_mfma_f32_16x16x32_bf16(
                    afl[mt], bfh[nt], acc[mt][nt], 0, 0, 0);
    }

    // --- epilogue: logits -> e (unnormalized), partial row stats -----------
    const float* lqu    = ws + W_LQU;
    const float* lqb    = ws + W_LQB;
    const float* bias   = ws + W_BIAS;
    const float* validf = ws + W_VALID;
    float* wout = dout + O_W;

    float ps[2][4], pm[2][4], pg[2][4], pu[2][4];
    #pragma unroll
    for (int mt = 0; mt < 2; ++mt)
        #pragma unroll
        for (int r = 0; r < 4; ++r) {
            ps[mt][r] = 0.f; pm[mt][r] = -1e30f; pg[mt][r] = 0.f; pu[mt][r] = 0.f;
        }

    #pragma unroll
    for (int mt = 0; mt < 2; ++mt) {
        const int rbase = row0 + wm * 32 + mt * 16 + fq * 4;
        #pragma unroll
        for (int nt = 0; nt < 4; ++nt) {
            const int uvb = n0 + wn * 64 + nt * 16;
            const int u   = uvb >> 6;
            const int uv  = uvb + fr;
            const int v   = uv & 63;
            const float bv = bias[uv];
            const float vd = validf[uv];
            const floatx4 a = acc[mt][nt];
            #pragma unroll
            for (int reg = 0; reg < 4; ++reg) {
                const int row = rbase + reg;
                const float jl  = fmaxf(lqu[(row << 6) + u] + lqb[(row << 6) + v], LOG1EM6);
                const float sig = fmaf(0.5f, a[reg], 0.5f);
                const float lg  = jl + bv + sig;
                const float e   = (vd > 0.f) ? __expf(lg - 2.f) : 0.f;
                wout[((size_t)row << 12) + uv] = e;
                ps[mt][reg] += e;
                if (vd > 0.f && lg > pm[mt][reg]) {
                    pm[mt][reg] = lg; pu[mt][reg] = (float)uv; pg[mt][reg] = sig;
                }
            }
        }
    }

    #pragma unroll
    for (int off = 1; off < 16; off <<= 1) {
        #pragma unroll
        for (int mt = 0; mt < 2; ++mt)
            #pragma unroll
            for (int r = 0; r < 4; ++r) {
                ps[mt][r] += __shfl_xor(ps[mt][r], off);
                float om = __shfl_xor(pm[mt][r], off);
                float ou = __shfl_xor(pu[mt][r], off);
                float og = __shfl_xor(pg[mt][r], off);
                if (om > pm[mt][r] || (om == pm[mt][r] && ou < pu[mt][r])) {
                    pm[mt][r] = om; pu[mt][r] = ou; pg[mt][r] = og;
                }
            }
    }
    if (fr == 0) {
        #pragma unroll
        for (int mt = 0; mt < 2; ++mt)
            #pragma unroll
            for (int r = 0; r < 4; ++r) {
                const int rl = wm * 32 + mt * 16 + fq * 4 + r;
                sS[wn][rl] = ps[mt][r]; sM[wn][rl] = pm[mt][r];
                sG[wn][rl] = pg[mt][r]; sU[wn][rl] = pu[mt][r];
            }
    }
    __syncthreads();
    if (tid < 64) {
        const float s  = sS[0][tid] + sS[1][tid];
        const float m0 = sM[0][tid], m1 = sM[1][tid];
        float m, uvf, g;
        if (m0 > m1 || (m0 == m1 && sU[0][tid] <= sU[1][tid])) {
            m = m0; uvf = sU[0][tid]; g = sG[0][tid];
        } else {
            m = m1; uvf = sU[1][tid]; g = sG[1][tid];
        }
        const int row = row0 + tid;
        ws[W_PSUM + cb * NT + row] = s;
        ws[W_PMAX + cb * NT + row] = m;
        ws[W_PSIG + cb * NT + row] = g;
        ws[W_PUV  + cb * NT + row] = uvf;
    }
}

// ---------------------------------------------------------------------------
// K3b: combine 32 col-block partials per row -> rinv, top_weight, conf.
// ---------------------------------------------------------------------------
__global__ __launch_bounds__(256)
void k3b_stats(float* __restrict__ ws, float* __restrict__ dout)
{
    const int row = blockIdx.x * 256 + threadIdx.x;         // 32 blocks
    float s = 0.f, m = -1e30f, uvf = 0.f, g = 0.f;
    for (int cb = 0; cb < 32; ++cb) {
        s += ws[W_PSUM + cb * NT + row];
        const float om = ws[W_PMAX + cb * NT + row];
        const float ou = ws[W_PUV  + cb * NT + row];
        const float og = ws[W_PSIG + cb * NT + row];
        if (om > m || (om == m && ou < uvf)) { m = om; uvf = ou; g = og; }
    }
    const float inv = 1.0f / s;
    ws[W_RINV + row] = inv;
    const float topw = __expf(m - 2.f) * inv;
    dout[O_TOPW + row] = topw;
    const int uvi = (int)uvf;
    const float cf = topw * ws[W_CONFN + uvi] * g;
    dout[O_CONF + row] = fminf(fmaxf(cf, 0.f), 1.f);
}

// ---------------------------------------------------------------------------
// K3c: normalize weights in place (e -> w), wide grid-strided float4 sweep.
// ---------------------------------------------------------------------------
__global__ __launch_bounds__(256)
void k3c_scale(const float* __restrict__ ws, float* __restrict__ dout)
{
    float4* wb = (float4*)(dout + O_W);
    const float* rinv = ws + W_RINV;
    const int t = blockIdx.x * 256 + threadIdx.x;           // 2048 blocks
    #pragma unroll 4
    for (int i = 0; i < 16; ++i) {
        const int idx = t + i * 524288;
        const float r = rinv[idx >> 10];
        float4 v = wb[idx];
        v.x *= r; v.y *= r; v.z *= r; v.w *= r;
        wb[idx] = v;
    }
}

// ---------------------------------------------------------------------------
// K4: MFMA GEMM2/3, 3-term bf16 split, K-split 4. BM=64 BN=192, grid
// (128 rowtiles, 2 coltiles, 4 ksplits) = 1024 blocks (4/CU via 40KB LDS).
// Each block covers K in [ks*1024, ks*1024+1024) (32 chunks of 32) and
// atomicAdds its partial C into d_out (delta/sig zeroed by memset before).
// Term-major MFMA order: 12 independent MFMAs back-to-back per term.
// ---------------------------------------------------------------------------
#define SA 40

__global__ __launch_bounds__(256, 4)
void k4_mfma(const float* __restrict__ ws_c, float* __restrict__ dout)
{
    __shared__ unsigned short sAh[64 * SA];
    __shared__ unsigned short sAl[64 * SA];
    __shared__ unsigned short sBh[192 * SA];
    __shared__ unsigned short sBl[192 * SA];

    const int tid  = threadIdx.x;
    const int row0 = blockIdx.x * 64;
    const int n0g  = blockIdx.y * 192;
    const int kb   = blockIdx.z * 1024;      // K-split base

    const float* wsrc = dout + O_W;
    const unsigned short* pth = (const unsigned short*)(ws_c + W_PTHI);
    const unsigned short* ptl = (const unsigned short*)(ws_c + W_PTLO);

    const int ar  = tid >> 3;
    const int akg = tid & 7;
    const int bn  = tid >> 2;
    const int bkg = tid & 3;

    float4 ap[2];
    uint4  bh[3], bl[3];
    {
        #pragma unroll
        for (int s = 0; s < 2; ++s)
            ap[s] = *(const float4*)&wsrc[(size_t)(row0 + ar + s * 32) * UV + kb + akg * 4];
        #pragma unroll
        for (int p = 0; p < 3; ++p) {
            const size_t bo = (size_t)(n0g + bn + p * 64) * UV + kb + bkg * 8;
            bh[p] = *(const uint4*)&pth[bo];
            bl[p] = *(const uint4*)&ptl[bo];
        }
    }

    const int lane = tid & 63;
    const int wid  = tid >> 6;
    const int wm   = wid & 1;
    const int wn   = wid >> 1;
    const int fr   = lane & 15;
    const int fq   = lane >> 4;
    const int ako  = fq * 8;

    floatx4 acc[2][6];
    #pragma unroll
    for (int mt = 0; mt < 2; ++mt)
        #pragma unroll
        for (int nt = 0; nt < 6; ++nt)
            acc[mt][nt] = (floatx4){0.f, 0.f, 0.f, 0.f};

    for (int kc = 0; kc < 32; ++kc) {
        __syncthreads();
        #pragma unroll
        for (int s = 0; s < 2; ++s) {
            const float xs[4] = {ap[s].x, ap[s].y, ap[s].z, ap[s].w};
            ushort4 h, l;
            h.x = f2bf(xs[0]); l.x = f2bf(xs[0] - bf2f(h.x));
            h.y = f2bf(xs[1]); l.y = f2bf(xs[1] - bf2f(h.y));
            h.z = f2bf(xs[2]); l.z = f2bf(xs[2] - bf2f(h.z));
            h.w = f2bf(xs[3]); l.w = f2bf(xs[3] - bf2f(h.w));
            const int r = ar + s * 32;
            *(ushort4*)&sAh[r * SA + akg * 4] = h;
            *(ushort4*)&sAl[r * SA + akg * 4] = l;
        }
        #pragma unroll
        for (int p = 0; p < 3; ++p) {
            const int n = bn + p * 64;
            *(uint4*)&sBh[n * SA + bkg * 8] = bh[p];
            *(uint4*)&sBl[n * SA + bkg * 8] = bl[p];
        }
        __syncthreads();

        if (kc + 1 < 32) {
            const int kn = kb + (kc + 1) * 32;
            #pragma unroll
            for (int s = 0; s < 2; ++s)
                ap[s] = *(const float4*)&wsrc[(size_t)(row0 + ar + s * 32) * UV + kn + akg * 4];
            #pragma unroll
            for (int p = 0; p < 3; ++p) {
                const size_t bo = (size_t)(n0g + bn + p * 64) * UV + kn + bkg * 8;
                bh[p] = *(const uint4*)&pth[bo];
                bl[p] = *(const uint4*)&ptl[bo];
            }
        }

        short8 afh[2], afl[2], bfh[6], bfl[6];
        #pragma unroll
        for (int mt = 0; mt < 2; ++mt) {
            const int m = wm * 32 + mt * 16 + fr;
            afh[mt] = *(const short8*)&sAh[m * SA + ako];
            afl[mt] = *(const short8*)&sAl[m * SA + ako];
        }
        #pragma unroll
        for (int nt = 0; nt < 6; ++nt) {
            const int n = wn * 96 + nt * 16 + fr;
            bfh[nt] = *(const short8*)&sBh[n * SA + ako];
            bfl[nt] = *(const short8*)&sBl[n * SA + ako];
        }
        // term-major: 12 independent MFMAs back-to-back per term
        #pragma unroll
        for (int mt = 0; mt < 2; ++mt)
            #pragma unroll
            for (int nt = 0; nt < 6; ++nt)
                acc[mt][nt] = __builtin_amdgcn_mfma_f32_16x16x32_bf16(
                    afh[mt], bfh[nt], acc[mt][nt], 0, 0, 0);
        #pragma unroll
        for (int mt = 0; mt < 2; ++mt)
            #pragma unroll
            for (int nt = 0; nt < 6; ++nt)
                acc[mt][nt] = __builtin_amdgcn_mfma_f32_16x16x32_bf16(
                    afh[mt], bfl[nt], acc[mt][nt], 0, 0, 0);
        #pragma unroll
        for (int mt = 0; mt < 2; ++mt)
            #pragma unroll
            for (int nt = 0; nt < 6; ++nt)
                acc[mt][nt] = __builtin_amdgcn_mfma_f32_16x16x32_bf16(
                    afl[mt], bfh[nt], acc[mt][nt], 0, 0, 0);
    }

    // epilogue: atomic accumulate partial C
    #pragma unroll
    for (int mt = 0; mt < 2; ++mt) {
        #pragma unroll
        for (int nt = 0; nt < 6; ++nt) {
            const int gr0 = row0 + wm * 32 + mt * 16 + fq * 4;
            const int gc  = n0g + wn * 96 + nt * 16 + fr;
            const floatx4 a = acc[mt][nt];
            if (gc < 256) {
                float* o = dout + O_DELTA;
                atomicAdd(&o[(size_t)(gr0 + 0) * 256 + gc], a[0]);
                atomicAdd(&o[(size_t)(gr0 + 1) * 256 + gc], a[1]);
                atomicAdd(&o[(size_t)(gr0 + 2) * 256 + gc], a[2]);
                atomicAdd(&o[(size_t)(gr0 + 3) * 256 + gc], a[3]);
            } else {
                float* o = dout + O_SIG;
                const int c = gc - 256;
                atomicAdd(&o[(size_t)(gr0 + 0) * 128 + c], a[0]);
                atomicAdd(&o[(size_t)(gr0 + 1) * 128 + c], a[1]);
                atomicAdd(&o[(size_t)(gr0 + 2) * 128 + c], a[2]);
                atomicAdd(&o[(size_t)(gr0 + 3) * 128 + c], a[3]);
            }
        }
    }
}

// ---------------------------------------------------------------------------
extern "C" void kernel_launch(void* const* d_in, const int* in_sizes, int n_in,
                              void* d_out, int out_size, void* d_ws, size_t ws_size,
                              hipStream_t stream)
{
    const float* qu   = (const float*)d_in[0];
    const float* qb   = (const float*)d_in[1];
    const float* qsig = (const float*)d_in[2];
    const float* drp  = (const float*)d_in[3];
    const float* spr  = (const float*)d_in[4];
    const float* wm   = (const float*)d_in[5];
    const float* ec   = (const float*)d_in[6];
    float* out = (float*)d_out;
    float* ws  = (float*)d_ws;

    // zero delta+sig regions (K-split k4 accumulates atomically)
    hipMemsetAsync(out, 0, (size_t)O_CONF * sizeof(float), stream);

    k1_tables<<<1, 256, 0, stream>>>(wm, ec, ws);
    k2_norm<<<3072, 256, 0, stream>>>(spr, qsig, ws);
    k2b_protoT<<<dim3(128, 12), 256, 0, stream>>>(drp, spr, ws);
    k2c_logs<<<dim3(512, 2), 256, 0, stream>>>(qu, qb, ws);
    k3_mfma<<<dim3(128, 32), 256, 0, stream>>>(ws, out);
    k3b_stats<<<32, 256, 0, stream>>>(ws, out);
    k3c_scale<<<2048, 256, 0, stream>>>(ws, out);
    k4_mfma<<<dim3(128, 2, 4), 256, 0, stream>>>(ws, out);
}